// Round 6
// baseline (724.588 us; speedup 1.0000x reference)
//
#include <hip/hip_runtime.h>

typedef int i4  __attribute__((ext_vector_type(4)));
typedef int i2  __attribute__((ext_vector_type(2)));
typedef int i4u __attribute__((ext_vector_type(4), aligned(4)));   // 4B-aligned 16B load

#define THREADS 256
#define WAVES_PB 4
#define K1_BLOCKS 4096     // pack: chunks of 1024 src elems, max 32768 = 4096*4*2
#define K1_ITERS 2
#define K2_BLOCKS 8192     // fanout: items of 1024 out elems, max 524288; 32768 waves
#define PK_OFF 256         // packed buffer offset within ws, in ints
#define WS_NEED ((size_t)4 * (PK_OFF + 32768u * 1024u))   // 134,218,752 B

// ws layout (uint32):
//  [0..8]   off16 : output prefix, off16[b] = sum_{j<b} 16*s_j^2
//  [9..17]  csum  : 1k-chunk prefix, csum[b] = sum_{j<b} ceil(s_j^2/1024)
//  [18..25] s[b]   [26..33] s2[b]   [34..41] inv_s[b] (float bits)
//  [PK_OFF..] packed bools as int32, batch b at csum[b]*1024 (padded per batch)
__global__ void setup_offsets_kernel(const int* __restrict__ seq,
                                     unsigned int* __restrict__ ws) {
    if (threadIdx.x == 0 && blockIdx.x == 0) {
        unsigned int o16 = 0, cs = 0;
        ws[0] = 0u; ws[9] = 0u;
        for (int b = 0; b < 8; ++b) {
            unsigned int s  = (unsigned int)seq[b];
            unsigned int s2 = s * s;
            o16 += 16u * s2;
            cs  += (s2 + 1023u) >> 10;
            ws[1 + b]  = o16;
            ws[10 + b] = cs;
            ws[18 + b] = s;
            ws[26 + b] = s2;
            ((float*)ws)[34 + b] = 1.0f / (float)s;
        }
    }
}

// ---------------- two-phase path ----------------

// Phase 1: pack mask[b,:s,:s] > 0.5 into packed int32, one copy (no heads).
__global__ void __launch_bounds__(THREADS)
pack_kernel(const float* __restrict__ mask, const unsigned int* __restrict__ ws,
            int* __restrict__ pk) {
    __shared__ unsigned int csum[9];
    __shared__ unsigned int slen[8];
    __shared__ unsigned int ssq[8];
    __shared__ float        sinv[8];
    int tx = threadIdx.x;
    if (tx < 9) csum[tx] = ws[9 + tx];
    if (tx < 8) {
        slen[tx] = ws[18 + tx];
        ssq[tx]  = ws[26 + tx];
        sinv[tx] = ((const float*)ws)[34 + tx];
    }
    __syncthreads();

    unsigned int nchunks     = csum[8];
    unsigned int total_waves = gridDim.x * WAVES_PB;
    unsigned int wave_id     = blockIdx.x * WAVES_PB + ((unsigned int)tx >> 6);
    unsigned int lane        = (unsigned int)tx & 63u;

#pragma unroll 1
    for (int it = 0; it < K1_ITERS; ++it) {
        unsigned int chunk = wave_id + (unsigned int)it * total_waves;
        if (chunk >= nchunks) break;

        unsigned int b = 0;
#pragma unroll
        for (int j = 1; j < 8; ++j) b += (chunk >= csum[j]) ? 1u : 0u;

        unsigned int s   = slen[b];
        unsigned int s2  = ssq[b];
        float        inv = sinv[b];
        unsigned int p0  = (chunk - csum[b]) << 10;
        unsigned int pb  = csum[b] << 10;          // packed base (mult of 1024)
        const float* mb  = mask + ((size_t)b << 22);

#pragma unroll
        for (int sub = 0; sub < 4; ++sub) {
            unsigned int p = p0 + ((unsigned int)sub << 8) + (lane << 2);
            if (p + 4u <= s2) {
                unsigned int row = (unsigned int)((float)p * inv);
                int col = (int)p - (int)(row * s);
                if (col < 0)            { row -= 1u; col += (int)s; }
                else if (col >= (int)s) { row += 1u; col -= (int)s; }
                unsigned int r0 = row;  int c0 = col;
                float v0 = mb[(size_t)r0 * 2048u + (unsigned int)c0];
                c0++; if (c0 == (int)s) { c0 = 0; r0++; }
                float v1 = mb[(size_t)r0 * 2048u + (unsigned int)c0];
                c0++; if (c0 == (int)s) { c0 = 0; r0++; }
                float v2 = mb[(size_t)r0 * 2048u + (unsigned int)c0];
                c0++; if (c0 == (int)s) { c0 = 0; r0++; }
                float v3 = mb[(size_t)r0 * 2048u + (unsigned int)c0];
                i4 o = (i4){(v0 > 0.5f) ? 1 : 0, (v1 > 0.5f) ? 1 : 0,
                            (v2 > 0.5f) ? 1 : 0, (v3 > 0.5f) ? 1 : 0};
                *(i4*)(pk + pb + p) = o;
            } else {
#pragma unroll
                for (int j = 0; j < 4; ++j) {
                    unsigned int pp = p + (unsigned int)j;
                    if (pp >= s2) continue;
                    unsigned int row = (unsigned int)((float)pp * inv);
                    int col = (int)pp - (int)(row * s);
                    if (col < 0)            { row -= 1u; col += (int)s; }
                    else if (col >= (int)s) { row += 1u; col -= (int)s; }
                    float v = mb[(size_t)row * 2048u + (unsigned int)col];
                    pk[pb + pp] = (v > 0.5f) ? 1 : 0;
                }
            }
        }
    }
}

// Phase 2: out[off16[b] + h*s2 + p] = packed[pb + p].  Item = 1024 out elems,
// item id = (chunkid<<4) | h  -> consecutive items share the source chunk and
// form 16 concurrent dense write fronts. Aligned i4 dest, 4B-aligned i4 src.
__global__ void __launch_bounds__(THREADS)
fanout_kernel(const unsigned int* __restrict__ ws, const int* __restrict__ pk,
              int* __restrict__ out) {
    __shared__ unsigned int off16[9];
    __shared__ unsigned int csum[9];
    __shared__ unsigned int ssq[8];
    int tx = threadIdx.x;
    if (tx < 9) { off16[tx] = ws[tx]; csum[tx] = ws[9 + tx]; }
    if (tx < 8) ssq[tx] = ws[26 + tx];
    __syncthreads();

    unsigned int nitems      = csum[8] << 4;
    unsigned int total_waves = gridDim.x * WAVES_PB;
    unsigned int W           = blockIdx.x * WAVES_PB + ((unsigned int)tx >> 6);
    unsigned int lane        = (unsigned int)tx & 63u;

#pragma unroll 1
    for (unsigned int item = W; item < nitems; item += total_waves) {
        unsigned int cid = item >> 4;
        unsigned int h   = item & 15u;

        unsigned int b = 0;
#pragma unroll
        for (int j = 1; j < 8; ++j) b += (cid >= csum[j]) ? 1u : 0u;

        unsigned int s2 = ssq[b];
        unsigned int c  = cid - csum[b];
        const int*  srcb = pk + (csum[b] << 10);   // index with (x - hb)

        unsigned int hb   = off16[b] + h * s2;     // head base in out
        unsigned int lo   = hb + (c << 10);
        unsigned int clen = s2 - (c << 10);
        if (clen > 1024u) clen = 1024u;
        unsigned int hi = lo + clen;

        unsigned int qs = (lo + 3u) >> 2;          // first aligned quad
        unsigned int qe = hi >> 2;                 // one past last aligned quad

#pragma unroll
        for (int k = 0; k < 4; ++k) {
            unsigned int q = qs + lane + ((unsigned int)k << 6);
            if (q < qe) {
                i4 v = *(const i4u*)(srcb + ((q << 2) - hb));
                *(i4*)(out + ((size_t)q << 2)) = v;
            }
        }
        if (lane < 3u) {
            unsigned int e = lo + lane;            // leading 0..3 scalars
            if (e < hi && e < (qs << 2)) out[e] = srcb[e - hb];
            unsigned int e2 = (qe << 2) + lane;    // trailing 0..3 scalars
            if (e2 >= lo && e2 < hi) out[e2] = srcb[e2 - hb];
        }
    }
}

// ---------------- fallback path (R4, best verified; NT reverted) ----------------

#define STORE_SHIFT(VV, SIG) do {                                              \
    *(i4*)(out + offh + 0   + (SIG)) = VV[0];                                  \
    *(i4*)(out + offh + 256 + (SIG)) = VV[1];                                  \
    *(i4*)(out + offh + 512 + (SIG)) = VV[2];                                  \
    if (lane < 63u) *(i4*)(out + offh + 768 + (SIG)) = VV[3];                  \
    if (lane == 0u) {                                                          \
        out[habase] = o[0].x;                                                  \
        if ((SIG) >= 2) out[habase + 1] = o[0].y;                              \
        if ((SIG) == 3) out[habase + 2] = o[0].z;                              \
    }                                                                          \
    if (lane == 63u) {                                                         \
        if ((SIG) == 1) out[habase + 1021] = o[3].y;                           \
        if ((SIG) <= 2) out[habase + 1022] = o[3].z;                           \
        out[habase + 1023] = o[3].w;                                           \
    }                                                                          \
} while (0)

__global__ void __launch_bounds__(THREADS)
unpad_mask_kernel_fb(const float* __restrict__ mask,
                     const unsigned int* __restrict__ ws,
                     int* __restrict__ out) {
    __shared__ unsigned int off16[9];
    __shared__ unsigned int csum[9];
    __shared__ unsigned int slen[8];
    __shared__ unsigned int ssq[8];
    __shared__ float        sinv[8];

    int tx = threadIdx.x;
    if (tx < 9) { off16[tx] = ws[tx]; csum[tx] = ws[9 + tx]; }
    if (tx < 8) {
        slen[tx] = ws[18 + tx];
        ssq[tx]  = ws[26 + tx];
        sinv[tx] = ((const float*)ws)[34 + tx];
    }
    __syncthreads();

    unsigned int nchunks     = csum[8];
    unsigned int total_waves = gridDim.x * WAVES_PB;
    unsigned int wave_id     = blockIdx.x * WAVES_PB + ((unsigned int)tx >> 6);
    unsigned int lane        = (unsigned int)tx & 63u;

#pragma unroll 1
    for (int it = 0; it < K1_ITERS; ++it) {
        unsigned int chunk = wave_id + (unsigned int)it * total_waves;
        if (chunk >= nchunks) break;

        unsigned int b = 0;
#pragma unroll
        for (int j = 1; j < 8; ++j) b += (chunk >= csum[j]) ? 1u : 0u;

        unsigned int s    = slen[b];
        unsigned int s2   = ssq[b];
        float        inv  = sinv[b];
        unsigned int p0   = (chunk - csum[b]) << 10;
        unsigned int base = off16[b];
        const float* mb   = mask + ((size_t)b << 22);

        if (s2 - p0 >= 1024u) {
            unsigned int q0 = p0 + (lane << 2);
            i4 o[4];
#pragma unroll
            for (int sub = 0; sub < 4; ++sub) {
                unsigned int q   = q0 + ((unsigned int)sub << 8);
                unsigned int row = (unsigned int)((float)q * inv);
                int col = (int)q - (int)(row * s);
                if (col < 0)            { row -= 1u; col += (int)s; }
                else if (col >= (int)s) { row += 1u; col -= (int)s; }
                unsigned int r0 = row;  int c0 = col;
                float v0 = mb[(size_t)r0 * 2048u + (unsigned int)c0];
                c0++; if (c0 == (int)s) { c0 = 0; r0++; }
                float v1 = mb[(size_t)r0 * 2048u + (unsigned int)c0];
                c0++; if (c0 == (int)s) { c0 = 0; r0++; }
                float v2 = mb[(size_t)r0 * 2048u + (unsigned int)c0];
                c0++; if (c0 == (int)s) { c0 = 0; r0++; }
                float v3 = mb[(size_t)r0 * 2048u + (unsigned int)c0];
                o[sub] = (i4){(v0 > 0.5f) ? 1 : 0, (v1 > 0.5f) ? 1 : 0,
                              (v2 > 0.5f) ? 1 : 0, (v3 > 0.5f) ? 1 : 0};
            }

            if ((s & 1u) == 0u) {
                unsigned int off = base + q0;
#pragma unroll
                for (int h = 0; h < 16; ++h) {
                    *(i4*)(out + off)       = o[0];
                    *(i4*)(out + off + 256) = o[1];
                    *(i4*)(out + off + 512) = o[2];
                    *(i4*)(out + off + 768) = o[3];
                    off += s2;
                }
            } else {
                int src = ((int)lane + 1) & 63;
                int sel = (lane == 0u) ? 1 : 0;
                int e0x = sel ? o[1].x : o[0].x;
                int e0y = sel ? o[1].y : o[0].y;
                int e0z = sel ? o[1].z : o[0].z;
                int e1x = sel ? o[2].x : o[1].x;
                int e1y = sel ? o[2].y : o[1].y;
                int e1z = sel ? o[2].z : o[1].z;
                int e2x = sel ? o[3].x : o[2].x;
                int e2y = sel ? o[3].y : o[2].y;
                int e2z = sel ? o[3].z : o[2].z;
                int n0x = __shfl(e0x, src, 64), n0y = __shfl(e0y, src, 64), n0z = __shfl(e0z, src, 64);
                int n1x = __shfl(e1x, src, 64), n1y = __shfl(e1y, src, 64), n1z = __shfl(e1z, src, 64);
                int n2x = __shfl(e2x, src, 64), n2y = __shfl(e2y, src, 64), n2z = __shfl(e2z, src, 64);
                int n3x = __shfl(o[3].x, src, 64), n3y = __shfl(o[3].y, src, 64), n3z = __shfl(o[3].z, src, 64);

                i4 v1[4], v2[4], v3[4];
                v1[0] = (i4){o[0].y, o[0].z, o[0].w, n0x};
                v1[1] = (i4){o[1].y, o[1].z, o[1].w, n1x};
                v1[2] = (i4){o[2].y, o[2].z, o[2].w, n2x};
                v1[3] = (i4){o[3].y, o[3].z, o[3].w, n3x};
                v2[0] = (i4){o[0].z, o[0].w, n0x, n0y};
                v2[1] = (i4){o[1].z, o[1].w, n1x, n1y};
                v2[2] = (i4){o[2].z, o[2].w, n2x, n2y};
                v2[3] = (i4){o[3].z, o[3].w, n3x, n3y};
                v3[0] = (i4){o[0].w, n0x, n0y, n0z};
                v3[1] = (i4){o[1].w, n1x, n1y, n1z};
                v3[2] = (i4){o[2].w, n2x, n2y, n2z};
                v3[3] = (i4){o[3].w, n3x, n3y, n3z};

                unsigned int habase = base + p0;
#pragma unroll
                for (int h = 0; h < 16; ++h) {
                    unsigned int offh = habase + (lane << 2);
                    const int r0c = h & 3;
                    if (r0c == 0) {
                        *(i4*)(out + offh)       = o[0];
                        *(i4*)(out + offh + 256) = o[1];
                        *(i4*)(out + offh + 512) = o[2];
                        *(i4*)(out + offh + 768) = o[3];
                    } else if (r0c == 1) {
                        STORE_SHIFT(v3, 3);
                    } else if (r0c == 2) {
                        STORE_SHIFT(v2, 2);
                    } else {
                        STORE_SHIFT(v1, 1);
                    }
                    habase += s2;
                }
            }
        } else {
#pragma unroll 1
            for (int sub = 0; sub < 4; ++sub) {
                unsigned int sp0 = p0 + ((unsigned int)sub << 8);
                if (sp0 >= s2) break;
#pragma unroll
                for (int j = 0; j < 4; ++j) {
                    unsigned int p = sp0 + (lane << 2) + (unsigned int)j;
                    if (p >= s2) continue;
                    unsigned int row = (unsigned int)((float)p * inv);
                    int col = (int)p - (int)(row * s);
                    if (col < 0)            { row -= 1u; col += (int)s; }
                    else if (col >= (int)s) { row += 1u; col -= (int)s; }
                    float v = mb[(size_t)row * 2048u + (unsigned int)col];
                    int o = (v > 0.5f) ? 1 : 0;
                    unsigned int off = base + p;
#pragma unroll
                    for (int h = 0; h < 16; ++h) {
                        out[off] = o;
                        off += s2;
                    }
                }
            }
        }
    }
}

extern "C" void kernel_launch(void* const* d_in, const int* in_sizes, int n_in,
                              void* d_out, int out_size, void* d_ws, size_t ws_size,
                              hipStream_t stream) {
    const float*  mask = (const float*)d_in[0];
    const int*    seq  = (const int*)d_in[1];
    unsigned int* ws   = (unsigned int*)d_ws;
    int*          out  = (int*)d_out;

    setup_offsets_kernel<<<1, 64, 0, stream>>>(seq, ws);
    if (ws_size >= WS_NEED) {
        int* pk = (int*)ws + PK_OFF;
        pack_kernel<<<K1_BLOCKS, THREADS, 0, stream>>>(mask, ws, pk);
        fanout_kernel<<<K2_BLOCKS, THREADS, 0, stream>>>(ws, pk, out);
    } else {
        unpad_mask_kernel_fb<<<K1_BLOCKS, THREADS, 0, stream>>>(mask, ws, out);
    }
}